// Round 8
// baseline (265.629 us; speedup 1.0000x reference)
//
#include <hip/hip_runtime.h>
#include <hip/hip_cooperative_groups.h>
namespace cg = cooperative_groups;

// ---------------------------------------------------------------------------
// DeepFFM round 8: ONE cooperative launch (4-launch fallback kept).
//  P0: prep   : X->bf16(pad), Mt build (LDS-cached nfk row), W0/W1/W2 -> bf16^T
//  P1: gemm12 : [T-partials | h0] = Xb @ [Mt ; Wt0]^T (N=2048, tri-K-skip)
//  P2: gemm3  : h1 = relu(h0 @ W1 + B1)
//  P3: gemm4  : BN=256 + fused out-dot + finalize -> out[]
// Phases separated by grid.sync(); 512 blocks x 256 thr, 64KB LDS union
// (2 blocks/CU co-residency). GEMM loop = R6-proven: stage(t+1) issued before
// compute(t), ONE __syncthreads per K-tile (prefetch overlap, race-free).
// R7's counted-vmcnt was reverted: stage(t+1) vs compute(t-1) raced in the
// same barrier interval (absmax 0.685) -> needs 3 buffers -> occupancy loss.
// ---------------------------------------------------------------------------

#define BATCH   4096
#define FSZ     1000
#define NFIELDS 39
#define KDIM    40

typedef __attribute__((ext_vector_type(8))) short short8v;  // 8 x bf16
typedef __attribute__((ext_vector_type(4))) float f32x4;

__device__ __forceinline__ short f2bf(float f) {
  unsigned u = __builtin_bit_cast(unsigned, f);
  u += 0x7fff + ((u >> 16) & 1);   // RNE (finite data)
  return (short)(u >> 16);
}
__device__ __forceinline__ float bf2f(unsigned short h) {
  unsigned u = (unsigned)h << 16;
  return __builtin_bit_cast(float, u);
}

typedef const __attribute__((address_space(1))) unsigned int* gas_ptr;
typedef __attribute__((address_space(3))) unsigned int* las_ptr;
__device__ __forceinline__ void gload16(const void* g, void* l) {
  __builtin_amdgcn_global_load_lds((gas_ptr)g, (las_ptr)l, 16, 0, 0);
}

// ---------------------------------------------------------------------------
// prep unit u (6784 units):
//  [0,4096)     : Xb row conversion (1000 -> 1024 pad)
//  [4096,5120)  : Mt row n (B12 rows 0..1023), nfk[n,:,:] cached in LDS
//  [5120,6144)  : W0^T -> B12 rows 1024..2047
//  [6144,6656)  : W1^T -> Wt1
//  [6656,6784)  : W2^T -> Wt2
// ---------------------------------------------------------------------------
__device__ __forceinline__ void transp32(
    const float* __restrict__ in, short* __restrict__ out, int idx, int nx,
    int K_in, int N_in, int Kpad, float (*t)[33], int tid)
{
  int n0 = (idx % nx) * 32, k0 = (idx / nx) * 32;
  int tx = tid & 31, ty = tid >> 5;
  #pragma unroll
  for (int i = 0; i < 32; i += 8) {
    int k = k0 + ty + i, n = n0 + tx;
    t[ty + i][tx] = (k < K_in && n < N_in) ? in[(size_t)k * N_in + n] : 0.f;
  }
  __syncthreads();
  #pragma unroll
  for (int i = 0; i < 32; i += 8) {
    int n = n0 + ty + i, k = k0 + tx;
    if (n < N_in && k < Kpad) out[(size_t)n * Kpad + k] = f2bf(t[tx][ty + i]);
  }
}

__device__ __forceinline__ void prep_unit(
    int u, int tid, char* sm,
    const float* __restrict__ X, const float* __restrict__ nfk,
    const int* __restrict__ f2f,
    const float* __restrict__ W0, const float* __restrict__ W1,
    const float* __restrict__ W2,
    short* __restrict__ Xb, short* __restrict__ B12,
    short* __restrict__ Wt1, short* __restrict__ Wt2)
{
  float (*tbuf)[33] = (float(*)[33])sm;          // 4224 B
  float* C = (float*)(sm + 4224);                // 39*44*4 = 6864 B
  if (u < 4096) {
    int k = tid * 4;
    short4 o = make_short4(0, 0, 0, 0);
    if (k < FSZ) {
      float4 v = *(const float4*)(X + (size_t)u * FSZ + k);
      o = make_short4(f2bf(v.x), f2bf(v.y), f2bf(v.z), f2bf(v.w));
    }
    *(short4*)(Xb + (size_t)u * 1024 + k) = o;
  } else if (u < 5120) {
    int n = u - 4096;
    if (n < FSZ) {
      for (int t = tid; t < NFIELDS * KDIM; t += 256)
        C[(t / KDIM) * 44 + (t % KDIM)] = nfk[(size_t)n * (NFIELDS * KDIM) + t];
    }
    __syncthreads();
    int fn = (n < FSZ) ? f2f[n] : 0;
    #pragma unroll
    for (int kk = 0; kk < 4; ++kk) {
      int k = kk * 256 + tid;
      float s = 0.f;
      if (n < FSZ && k < n) {
        int fk = f2f[k];
        const float4* p = (const float4*)(nfk + ((size_t)k * NFIELDS + fn) * KDIM);
        const float4* q = (const float4*)&C[fk * 44];
        #pragma unroll
        for (int t = 0; t < KDIM / 4; ++t) {
          float4 a = p[t], b = q[t];
          s += a.x * b.x + a.y * b.y + a.z * b.z + a.w * b.w;
        }
      }
      B12[(size_t)n * 1024 + k] = f2bf(s);
    }
  } else if (u < 6144) {
    transp32(W0, B12 + 1024 * 1024, u - 5120, 32, 1000, 1024, 1024, tbuf, tid);
  } else if (u < 6656) {
    transp32(W1, Wt1, u - 6144, 16, 1024, 512, 1024, tbuf, tid);
  } else {
    transp32(W2, Wt2, u - 6656, 8, 512, 256, 512, tbuf, tid);
  }
}

// ---------------------------------------------------------------------------
// GEMM body (R6-proven loop). A: MxK bf16; Bt: NxK bf16 (=B^T).
// 256 thr, 4 waves 2x2. DB (EPI!=3): double-buffered prefetch, 1 barrier/tile.
// EPI 3: single-buffered serial loop (fits 64KB union), tiny kernel.
// EPI 0: dual (bx<8: interaction+linear partials, tri-K-skip, Xb-based;
//        bx>=8: h0 bf16 relu, stride 1024)
// EPI 1: bf16 + bias + relu
// EPI 3: out[r] = sum_c relu(acc+bias[c])*oW[c] + sum_8 part[r] + b0 + outB
// ---------------------------------------------------------------------------
template<int BM, int BN, int EPI>
__device__ __forceinline__ void gemm_body(
    char* sm, int bx, int by,
    const short* __restrict__ A, const short* __restrict__ Bt,
    const float* __restrict__ bias, void* __restrict__ Cout,
    int N, int K,
    const short* __restrict__ Xb, const float* __restrict__ w1,
    float* __restrict__ partial,
    const float* __restrict__ c1, const float* __restrict__ c2)
{
  constexpr int AM = BM / 32, AN = BN / 32;
  constexpr bool DB = (EPI != 3);
  constexpr int ABUF = 128 * BM;   // bytes per A LDS buffer (BM*64 bf16)
  constexpr int BBUF = 128 * BN;
  char* Asb = sm;
  char* Bsb = sm + (DB ? 2 * ABUF : ABUF);
  float (*pb)[BM] = (float(*)[BM])sm;   // alias As; used only after barrier

  const int tid  = threadIdx.x;
  const int wid  = tid >> 6;
  const int lane = tid & 63;
  const int wr   = wid >> 1, wc = wid & 1;
  const int row0 = by * BM;
  const int col0 = bx * BN;
  const int lr8   = lane >> 3;
  const int cbase = (lane & 7) * 16;

  f32x4 acc[AM][AN];
  #pragma unroll
  for (int m = 0; m < AM; ++m)
    #pragma unroll
    for (int n = 0; n < AN; ++n) acc[m][n] = (f32x4)(0.f);

  auto stage = [&](int p, int k0) {
    #pragma unroll
    for (int j = 0; j < BM / 32; ++j) {
      int i = j * 4 + wid;
      int r = i * 8 + lr8;
      int cb = cbase ^ ((r & 7) << 4);   // pre-swizzled global source
      gload16((const char*)A + (((size_t)(row0 + r) * K + k0) << 1) + cb,
              Asb + p * ABUF + i * 1024);
    }
    #pragma unroll
    for (int j = 0; j < BN / 32; ++j) {
      int i = j * 4 + wid;
      int r = i * 8 + lr8;
      int cb = cbase ^ ((r & 7) << 4);
      gload16((const char*)Bt + (((size_t)(col0 + r) * K + k0) << 1) + cb,
              Bsb + p * BBUF + i * 1024);
    }
  };

  auto compute = [&](int p) {
    #pragma unroll
    for (int kk = 0; kk < 2; ++kk) {
      const int cb = kk * 64 + (lane >> 4) * 16;
      short8v a[AM], b[AN];
      #pragma unroll
      for (int m = 0; m < AM; ++m) {
        int r = wr * (BM / 2) + m * 16 + (lane & 15);
        a[m] = *(const short8v*)(Asb + p * ABUF + r * 128 + (cb ^ ((r & 7) << 4)));
      }
      #pragma unroll
      for (int n = 0; n < AN; ++n) {
        int r = wc * (BN / 2) + n * 16 + (lane & 15);
        b[n] = *(const short8v*)(Bsb + p * BBUF + r * 128 + (cb ^ ((r & 7) << 4)));
      }
      #pragma unroll
      for (int m = 0; m < AM; ++m)
        #pragma unroll
        for (int n = 0; n < AN; ++n)
          acc[m][n] = __builtin_amdgcn_mfma_f32_16x16x32_bf16(a[m], b[n], acc[m][n], 0, 0, 0);
    }
  };

  // Triangular K-skip: interaction cols [col0, col0+BN) only need k < col0+BN
  int nt = K >> 6;
  if (EPI == 0 && bx < 8) {
    int need = bx * 2 + 2;
    nt = nt < need ? nt : need;
  }

  if constexpr (DB) {
    // stage(t+1) issued before compute(t); overwrite of buf p^1 vs its last
    // read (compute(t-1)) is separated by the end-of-iteration barrier.
    stage(0, 0);
    __syncthreads();
    for (int t = 0; t < nt; ++t) {
      if (t + 1 < nt) stage((t + 1) & 1, (t + 1) << 6);
      compute(t & 1);
      __syncthreads();
    }
  } else {
    for (int t = 0; t < nt; ++t) {
      __syncthreads();
      stage(0, t << 6);
      asm volatile("s_waitcnt vmcnt(0)" ::: "memory");
      __syncthreads();
      compute(0);
    }
    __syncthreads();   // before pbuf (aliases As) is written
  }

  const int cr = (lane >> 4) * 4;
  const int cc = lane & 15;

  if (EPI == 0) {
    if (bx < 8) {
      // interaction + linear partials: sum_c (acc + w1[c]) * Xb[r][c]
      float rsum[AM * 4];
      #pragma unroll
      for (int i = 0; i < AM * 4; ++i) rsum[i] = 0.f;
      #pragma unroll
      for (int m = 0; m < AM; ++m) {
        #pragma unroll
        for (int n = 0; n < AN; ++n) {
          int gc = col0 + wc * (BN / 2) + n * 16 + cc;
          float w1v = (gc < FSZ) ? w1[gc] : 0.f;
          #pragma unroll
          for (int r = 0; r < 4; ++r) {
            int gr = row0 + wr * (BM / 2) + m * 16 + cr + r;
            float xv = bf2f((unsigned short)Xb[(size_t)gr * 1024 + gc]);
            rsum[m * 4 + r] = fmaf(acc[m][n][r] + w1v, xv, rsum[m * 4 + r]);
          }
        }
      }
      #pragma unroll
      for (int mask = 1; mask < 16; mask <<= 1)
        #pragma unroll
        for (int i = 0; i < AM * 4; ++i)
          rsum[i] += __shfl_xor(rsum[i], mask, 64);
      if (cc == 0) {
        #pragma unroll
        for (int m = 0; m < AM; ++m)
          #pragma unroll
          for (int r = 0; r < 4; ++r)
            pb[wc][wr * (BM / 2) + m * 16 + cr + r] = rsum[m * 4 + r];
      }
      __syncthreads();
      if (tid < BM)
        partial[(size_t)(row0 + tid) * 8 + bx] = pb[0][tid] + pb[1][tid];
    } else {
      // h0 = relu(X@W0 + B0), bf16, stride 1024
      #pragma unroll
      for (int m = 0; m < AM; ++m) {
        #pragma unroll
        for (int n = 0; n < AN; ++n) {
          int gc = col0 - 1024 + wc * (BN / 2) + n * 16 + cc;
          float bv = bias[gc];
          #pragma unroll
          for (int r = 0; r < 4; ++r) {
            int gr = row0 + wr * (BM / 2) + m * 16 + cr + r;
            float v = fmaxf(acc[m][n][r] + bv, 0.f);
            ((short*)Cout)[(size_t)gr * 1024 + gc] = f2bf(v);
          }
        }
      }
    }
  } else if (EPI == 1) {
    #pragma unroll
    for (int m = 0; m < AM; ++m) {
      #pragma unroll
      for (int n = 0; n < AN; ++n) {
        int gc = col0 + wc * (BN / 2) + n * 16 + cc;
        float bv = bias[gc];
        #pragma unroll
        for (int r = 0; r < 4; ++r) {
          int gr = row0 + wr * (BM / 2) + m * 16 + cr + r;
          float v = fmaxf(acc[m][n][r] + bv, 0.f);
          ((short*)Cout)[(size_t)gr * N + gc] = f2bf(v);
        }
      }
    }
  } else {
    // EPI 3: out[r] = sum_c relu(acc+bias[c])*oW[c] + sum_8 part[r] + c1 + c2
    float rsum[AM * 4];
    #pragma unroll
    for (int i = 0; i < AM * 4; ++i) rsum[i] = 0.f;
    #pragma unroll
    for (int m = 0; m < AM; ++m) {
      #pragma unroll
      for (int n = 0; n < AN; ++n) {
        int gc = col0 + wc * (BN / 2) + n * 16 + cc;
        float bv = bias[gc];
        float ow = w1[gc];
        #pragma unroll
        for (int r = 0; r < 4; ++r) {
          float v = fmaxf(acc[m][n][r] + bv, 0.f);
          rsum[m * 4 + r] = fmaf(v, ow, rsum[m * 4 + r]);
        }
      }
    }
    #pragma unroll
    for (int mask = 1; mask < 16; mask <<= 1)
      #pragma unroll
      for (int i = 0; i < AM * 4; ++i)
        rsum[i] += __shfl_xor(rsum[i], mask, 64);
    if (cc == 0) {
      #pragma unroll
      for (int m = 0; m < AM; ++m)
        #pragma unroll
        for (int r = 0; r < 4; ++r)
          pb[wc][wr * (BM / 2) + m * 16 + cr + r] = rsum[m * 4 + r];
    }
    __syncthreads();
    if (tid < BM) {
      int gr = row0 + tid;
      const float4* pp = (const float4*)(partial + (size_t)gr * 8);
      float4 u = pp[0], v = pp[1];
      ((float*)Cout)[gr] = pb[0][tid] + pb[1][tid]
          + u.x + u.y + u.z + u.w + v.x + v.y + v.z + v.w + c1[0] + c2[0];
    }
  }
}

// ---------------------------------------------------------------------------
// Fused cooperative kernel: 512 blocks x 256 thr, 64KB LDS (2 blocks/CU).
// ---------------------------------------------------------------------------
__global__ __launch_bounds__(256, 2) void fused_kernel(
    const float* X, const float* w1, const float* bsc, const float* nfk,
    const int* f2f, const float* W0, const float* B0, const float* W1,
    const float* B1, const float* W2, const float* B2, const float* oW,
    const float* oB, float* out,
    short* Xb, short* B12, short* Wt1, short* Wt2,
    float* part, short* h0, short* h1)
{
  __shared__ __align__(16) char smem[65536];
  cg::grid_group grid = cg::this_grid();
  const int bid = blockIdx.x, tid = threadIdx.x;

  // P0: prep (6784 units over 512 blocks)
  for (int u = bid; u < 6784; u += 512) {
    prep_unit(u, tid, smem, X, nfk, f2f, W0, W1, W2, Xb, B12, Wt1, Wt2);
    __syncthreads();
  }
  grid.sync();
  // P1: gemm12  (16 x 32 blocks)
  gemm_body<128, 128, 0>(smem, bid & 15, bid >> 4, Xb, B12, B0, h0,
                         2048, 1024, Xb, w1, part, nullptr, nullptr);
  grid.sync();
  // P2: gemm3   (8 x 64 blocks)
  gemm_body<64, 64, 1>(smem, bid & 7, bid >> 3, h0, Wt1, B1, h1,
                       512, 1024, nullptr, nullptr, nullptr, nullptr, nullptr);
  grid.sync();
  // P3: gemm4 + out-dot + finalize (128 blocks; rest exit)
  if (bid < 128)
    gemm_body<32, 256, 3>(smem, 0, bid, h1, Wt2, B2, out,
                          256, 512, nullptr, oW, part, bsc, oB);
}

// ---------------------------------------------------------------------------
// Fallback wrappers (4-launch path, identical math)
// ---------------------------------------------------------------------------
__global__ __launch_bounds__(256) void prep_kernel(
    const float* X, const float* nfk, const int* f2f,
    const float* W0, const float* W1, const float* W2,
    short* Xb, short* B12, short* Wt1, short* Wt2)
{
  __shared__ __align__(16) char smem[11136];
  prep_unit(blockIdx.x, threadIdx.x, smem, X, nfk, f2f, W0, W1, W2,
            Xb, B12, Wt1, Wt2);
}

template<int BM, int BN, int EPI>
__global__ __launch_bounds__(256) void gemm_mfma(
    const short* A, const short* Bt, const float* bias, void* Cout,
    int N, int K, const short* Xb, const float* w1, float* partial,
    const float* c1, const float* c2)
{
  constexpr int SM = (EPI != 3) ? 256 * (BM + BN) : 128 * (BM + BN);
  __shared__ __align__(16) char smem[SM];
  gemm_body<BM, BN, EPI>(smem, blockIdx.x, blockIdx.y, A, Bt, bias, Cout,
                         N, K, Xb, w1, partial, c1, c2);
}

// ---------------------------------------------------------------------------
extern "C" void kernel_launch(void* const* d_in, const int* in_sizes, int n_in,
                              void* d_out, int out_size, void* d_ws, size_t ws_size,
                              hipStream_t stream) {
  const float* X   = (const float*)d_in[0];
  const float* w1  = (const float*)d_in[1];
  const float* bsc = (const float*)d_in[2];
  const float* nfk = (const float*)d_in[3];
  const int*   f2f = (const int*)d_in[4];
  const float* W0  = (const float*)d_in[5];
  const float* B0  = (const float*)d_in[6];
  const float* W1  = (const float*)d_in[7];
  const float* B1  = (const float*)d_in[8];
  const float* W2  = (const float*)d_in[9];
  const float* B2  = (const float*)d_in[10];
  const float* oW  = (const float*)d_in[11];
  const float* oB  = (const float*)d_in[12];
  float* out = (float*)d_out;

  char* ws = (char*)d_ws;
  short* Xb   = (short*)(ws);                 // 8,388,608
  short* B12  = (short*)(ws + 8388608);       // 4,194,304 (Mt 0..1023, Wt0 1024..2047)
  short* Wt1  = (short*)(ws + 12582912);      // 1,048,576
  short* Wt2  = (short*)(ws + 13631488);      //   262,144
  float* part = (float*)(ws + 13893632);      //   131,072 (4096 x 8)
  short* h0   = (short*)(ws + 14680064);      // 8,388,608
  short* h1   = (short*)(ws + 23068672);      // 4,194,304  -> total 27,262,976 B

  void* args[] = {
    (void*)&X, (void*)&w1, (void*)&bsc, (void*)&nfk, (void*)&f2f,
    (void*)&W0, (void*)&B0, (void*)&W1, (void*)&B1, (void*)&W2, (void*)&B2,
    (void*)&oW, (void*)&oB, (void*)&out,
    (void*)&Xb, (void*)&B12, (void*)&Wt1, (void*)&Wt2,
    (void*)&part, (void*)&h0, (void*)&h1 };

  hipError_t err = hipLaunchCooperativeKernel(
      (const void*)fused_kernel, dim3(512), dim3(256), args, 0, stream);

  if (err != hipSuccess) {
    // deterministic fallback: identical math, 4 launches
    prep_kernel<<<6784, 256, 0, stream>>>(X, nfk, f2f, W0, W1, W2,
                                          Xb, B12, Wt1, Wt2);
    gemm_mfma<128, 128, 0><<<dim3(16, 32), 256, 0, stream>>>(
        Xb, B12, B0, h0, 2048, 1024, Xb, w1, part, nullptr, nullptr);
    gemm_mfma<64, 64, 1><<<dim3(8, 64), 256, 0, stream>>>(
        h0, Wt1, B1, h1, 512, 1024, nullptr, nullptr, nullptr, nullptr, nullptr);
    gemm_mfma<32, 256, 3><<<dim3(1, 128), 256, 0, stream>>>(
        h1, Wt2, B2, out, 256, 512, nullptr, oW, part, bsc, oB);
  }
}

// Round 9
// 73.900 us; speedup vs baseline: 3.5944x; 3.5944x over previous
//
#include <hip/hip_runtime.h>

// ---------------------------------------------------------------------------
// DeepFFM round 9: 5 launches (R6 GEMM core + XCD swizzle + coalesced Mt).
//  1) prep_a   : X->bf16(pad), W0/W1/W2 -> bf16^T, nfkT transpose (39x1000x40)
//  2) prep_b   : Mt build from nfkT (fully coalesced k-row reads)
//  3) gemm12   : [T-partials | h0] = Xb @ [Mt ; Wt0]^T  (N=2048, tri-K-skip)
//  4) gemm3    : h1 = relu(h0 @ W1 + B1)   (64x64 tiles, 512 blocks)
//  5) gemm4    : BN=256 (full N) + fused out-dot + finalize -> writes out[]
// GEMMs: bf16 MFMA 16x16x32, fp32 acc, double-buffered LDS, R6-proven
// prefetch loop (stage(t+1) before compute(t), ONE barrier per K-tile),
// XOR-swizzled LDS, XCD-chunked blockIdx swizzle (T1; all grids %8==0).
// R8 lesson: grid.sync() on 8 XCDs = L2 flush per sync -> 3.4x slower. Dead end.
// ---------------------------------------------------------------------------

#define BATCH   4096
#define FSZ     1000
#define NFIELDS 39
#define KDIM    40

typedef __attribute__((ext_vector_type(8))) short short8v;  // 8 x bf16
typedef __attribute__((ext_vector_type(4))) float f32x4;

__device__ __forceinline__ short f2bf(float f) {
  unsigned u = __builtin_bit_cast(unsigned, f);
  u += 0x7fff + ((u >> 16) & 1);   // RNE (finite data)
  return (short)(u >> 16);
}
__device__ __forceinline__ float bf2f(unsigned short h) {
  unsigned u = (unsigned)h << 16;
  return __builtin_bit_cast(float, u);
}

typedef const __attribute__((address_space(1))) unsigned int* gas_ptr;
typedef __attribute__((address_space(3))) unsigned int* las_ptr;
__device__ __forceinline__ void gload16(const void* g, void* l) {
  __builtin_amdgcn_global_load_lds((gas_ptr)g, (las_ptr)l, 16, 0, 0);
}

// ---------------------------------------------------------------------------
// prep_a: block ranges
//  [0,4096)     : Xb row conversion (1000 -> 1024 pad)
//  [4096,5120)  : W0^T -> B12 rows 1024..2047
//  [5120,5632)  : W1^T -> Wt1
//  [5632,5760)  : W2^T -> Wt2
//  [5760,5916)  : nfkT[g][j][k] = nfk[j][g][k]  (156 blocks: 39g x 4 j-chunks)
// ---------------------------------------------------------------------------
__device__ __forceinline__ void transp32(
    const float* __restrict__ in, short* __restrict__ out, int idx, int nx,
    int K_in, int N_in, int Kpad, float (*t)[33], int tid)
{
  int n0 = (idx % nx) * 32, k0 = (idx / nx) * 32;
  int tx = tid & 31, ty = tid >> 5;
  #pragma unroll
  for (int i = 0; i < 32; i += 8) {
    int k = k0 + ty + i, n = n0 + tx;
    t[ty + i][tx] = (k < K_in && n < N_in) ? in[(size_t)k * N_in + n] : 0.f;
  }
  __syncthreads();
  #pragma unroll
  for (int i = 0; i < 32; i += 8) {
    int n = n0 + ty + i, k = k0 + tx;
    if (n < N_in && k < Kpad) out[(size_t)n * Kpad + k] = f2bf(t[tx][ty + i]);
  }
}

__global__ __launch_bounds__(256) void prep_a_kernel(
    const float* __restrict__ X, const float* __restrict__ nfk,
    const float* __restrict__ W0, const float* __restrict__ W1,
    const float* __restrict__ W2,
    short* __restrict__ Xb, short* __restrict__ B12,
    short* __restrict__ Wt1, short* __restrict__ Wt2,
    float* __restrict__ nfkT)
{
  __shared__ float tbuf[32][33];
  const int bid = blockIdx.x, tid = threadIdx.x;
  if (bid < 4096) {
    int k = tid * 4;
    short4 o = make_short4(0, 0, 0, 0);
    if (k < FSZ) {
      float4 v = *(const float4*)(X + (size_t)bid * FSZ + k);
      o = make_short4(f2bf(v.x), f2bf(v.y), f2bf(v.z), f2bf(v.w));
    }
    *(short4*)(Xb + (size_t)bid * 1024 + k) = o;
  } else if (bid < 5120) {
    transp32(W0, B12 + 1024 * 1024, bid - 4096, 32, 1000, 1024, 1024, tbuf, tid);
  } else if (bid < 5632) {
    transp32(W1, Wt1, bid - 5120, 16, 1024, 512, 1024, tbuf, tid);
  } else if (bid < 5760) {
    transp32(W2, Wt2, bid - 5632, 8, 512, 256, 512, tbuf, tid);
  } else {
    // nfkT transpose: read nfk[j][g][:] (160B segments), write coalesced
    int idx = bid - 5760;
    int g = idx >> 2, jc = idx & 3;
    int j = jc * 256 + tid;
    if (j < FSZ && g < NFIELDS) {
      const float4* src = (const float4*)(nfk + ((size_t)j * NFIELDS + g) * KDIM);
      float4* dst = (float4*)(nfkT + ((size_t)g * FSZ + j) * KDIM);
      #pragma unroll
      for (int t = 0; t < KDIM / 4; ++t) dst[t] = src[t];
    }
  }
}

// ---------------------------------------------------------------------------
// prep_b: Mt row n (B12 rows 0..1023). nfk[n] cached in LDS; p-side reads
// nfkT[fn][k][:] -> consecutive threads k read CONTIGUOUS 160B rows.
// ---------------------------------------------------------------------------
__global__ __launch_bounds__(256) void prep_b_kernel(
    const float* __restrict__ nfk, const float* __restrict__ nfkT,
    const int* __restrict__ f2f, short* __restrict__ B12)
{
  __shared__ float C[NFIELDS * 44];  // nfk[n,:,:], stride 44 (16B-aligned)
  const int n = blockIdx.x, tid = threadIdx.x;
  if (n < FSZ) {
    for (int t = tid; t < NFIELDS * KDIM; t += 256)
      C[(t / KDIM) * 44 + (t % KDIM)] = nfk[(size_t)n * (NFIELDS * KDIM) + t];
  }
  __syncthreads();
  int fn = (n < FSZ) ? f2f[n] : 0;
  const float* pbase = nfkT + (size_t)fn * FSZ * KDIM;
  #pragma unroll
  for (int kk = 0; kk < 4; ++kk) {
    int k = kk * 256 + tid;
    float s = 0.f;
    if (n < FSZ && k < n) {
      int fk = f2f[k];
      const float4* p = (const float4*)(pbase + (size_t)k * KDIM);
      const float4* q = (const float4*)&C[fk * 44];
      #pragma unroll
      for (int t = 0; t < KDIM / 4; ++t) {
        float4 a = p[t], b = q[t];
        s += a.x * b.x + a.y * b.y + a.z * b.z + a.w * b.w;
      }
    }
    B12[(size_t)n * 1024 + k] = f2bf(s);
  }
}

// ---------------------------------------------------------------------------
// bf16 MFMA GEMM, double-buffered prefetch (R6-proven). A: MxK; Bt: NxK (=B^T).
// 256 thr, 4 waves 2x2, wave tile (BM/2)x(BN/2), frags AM=BM/32, AN=BN/32.
// XCD-chunked swizzle: blocks lin%8==r (-> XCD r) get contiguous logical
// tiles (A-panels fetched once per XCD instead of 8x).
// EPI 0: dual (bx<8: interaction+linear partials, tri-K-skip, Xb-based;
//        bx>=8: h0 bf16 relu, stride 1024)
// EPI 1: bf16 + bias + relu
// EPI 3: fused out-dot + finalize: out[r] = sum_c relu(acc+bias[c])*oW[c]
//        + sum_8 part[r] + b0 + outB      (requires BN == N)
// ---------------------------------------------------------------------------
template<int BM, int BN, int EPI>
__global__ __launch_bounds__(256) void gemm_mfma(
    const short* __restrict__ A, const short* __restrict__ Bt,
    const float* __restrict__ bias, void* __restrict__ Cout,
    int N, int K,
    const short* __restrict__ Xb, const float* __restrict__ w1,
    float* __restrict__ partial,
    const float* __restrict__ c1, const float* __restrict__ c2)
{
  constexpr int AM = BM / 32, AN = BN / 32;
  __shared__ __align__(16) short As[2][BM * 64];
  __shared__ __align__(16) short Bs[2][BN * 64];
  __shared__ float pbuf[2][BM];

  // XCD-chunked bijective swizzle (nwg % 8 == 0 for all our grids)
  const int nwgx = gridDim.x;
  const int lin  = blockIdx.y * nwgx + blockIdx.x;
  const int cpx  = (nwgx * gridDim.y) >> 3;
  const int slin = (lin & 7) * cpx + (lin >> 3);
  const int bx   = slin % nwgx;
  const int by   = slin / nwgx;

  const int tid  = threadIdx.x;
  const int wid  = tid >> 6;
  const int lane = tid & 63;
  const int wr   = wid >> 1, wc = wid & 1;
  const int row0 = by * BM;
  const int col0 = bx * BN;

  const int lr8   = lane >> 3;        // chunk-local row 0..7
  const int cbase = (lane & 7) * 16;  // byte col within 128B row

  f32x4 acc[AM][AN];
  #pragma unroll
  for (int m = 0; m < AM; ++m)
    #pragma unroll
    for (int n = 0; n < AN; ++n) acc[m][n] = (f32x4)(0.f);

  auto stage = [&](int p, int k0) {
    #pragma unroll
    for (int j = 0; j < BM / 32; ++j) {
      int i = j * 4 + wid;               // 1 KiB chunk = 8 rows
      int r = i * 8 + lr8;
      int cb = cbase ^ ((r & 7) << 4);   // pre-swizzled global source
      gload16((const char*)A + (((size_t)(row0 + r) * K + k0) << 1) + cb,
              (char*)&As[p][0] + i * 1024);
    }
    #pragma unroll
    for (int j = 0; j < BN / 32; ++j) {
      int i = j * 4 + wid;
      int r = i * 8 + lr8;
      int cb = cbase ^ ((r & 7) << 4);
      gload16((const char*)Bt + (((size_t)(col0 + r) * K + k0) << 1) + cb,
              (char*)&Bs[p][0] + i * 1024);
    }
  };

  auto compute = [&](int p) {
    #pragma unroll
    for (int kk = 0; kk < 2; ++kk) {
      const int cb = kk * 64 + (lane >> 4) * 16;
      short8v a[AM], b[AN];
      #pragma unroll
      for (int m = 0; m < AM; ++m) {
        int r = wr * (BM / 2) + m * 16 + (lane & 15);
        a[m] = *(const short8v*)((const char*)&As[p][0] + r * 128 + (cb ^ ((r & 7) << 4)));
      }
      #pragma unroll
      for (int n = 0; n < AN; ++n) {
        int r = wc * (BN / 2) + n * 16 + (lane & 15);
        b[n] = *(const short8v*)((const char*)&Bs[p][0] + r * 128 + (cb ^ ((r & 7) << 4)));
      }
      #pragma unroll
      for (int m = 0; m < AM; ++m)
        #pragma unroll
        for (int n = 0; n < AN; ++n)
          acc[m][n] = __builtin_amdgcn_mfma_f32_16x16x32_bf16(a[m], b[n], acc[m][n], 0, 0, 0);
    }
  };

  // Triangular K-skip: interaction cols [col0, col0+BN) only need k < col0+BN
  int nt = K >> 6;
  if (EPI == 0 && bx < 8) {
    int need = bx * 2 + 2;
    nt = nt < need ? nt : need;
  }

  // R6-proven pipeline: stage(t+1) issued BEFORE compute(t); one barrier/tile.
  stage(0, 0);
  __syncthreads();
  for (int t = 0; t < nt; ++t) {
    if (t + 1 < nt) stage((t + 1) & 1, (t + 1) << 6);  // prefetch (in flight)
    compute(t & 1);                                     // overlaps with loads
    __syncthreads();                    // drain loads + compute-done handoff
  }

  const int cr = (lane >> 4) * 4;
  const int cc = lane & 15;

  if (EPI == 0) {
    if (bx < 8) {
      // interaction + linear partials: sum_c (acc + w1[c]) * Xb[r][c]
      float rsum[AM * 4];
      #pragma unroll
      for (int i = 0; i < AM * 4; ++i) rsum[i] = 0.f;
      #pragma unroll
      for (int m = 0; m < AM; ++m) {
        #pragma unroll
        for (int n = 0; n < AN; ++n) {
          int gc = col0 + wc * (BN / 2) + n * 16 + cc;
          float w1v = (gc < FSZ) ? w1[gc] : 0.f;
          #pragma unroll
          for (int r = 0; r < 4; ++r) {
            int gr = row0 + wr * (BM / 2) + m * 16 + cr + r;
            float xv = bf2f((unsigned short)Xb[(size_t)gr * 1024 + gc]);
            rsum[m * 4 + r] = fmaf(acc[m][n][r] + w1v, xv, rsum[m * 4 + r]);
          }
        }
      }
      #pragma unroll
      for (int mask = 1; mask < 16; mask <<= 1)
        #pragma unroll
        for (int i = 0; i < AM * 4; ++i)
          rsum[i] += __shfl_xor(rsum[i], mask, 64);
      if (cc == 0) {
        #pragma unroll
        for (int m = 0; m < AM; ++m)
          #pragma unroll
          for (int r = 0; r < 4; ++r)
            pbuf[wc][wr * (BM / 2) + m * 16 + cr + r] = rsum[m * 4 + r];
      }
      __syncthreads();
      if (tid < BM)
        partial[(size_t)(row0 + tid) * 8 + bx] = pbuf[0][tid] + pbuf[1][tid];
    } else {
      // h0 = relu(X@W0 + B0), bf16, stride 1024
      #pragma unroll
      for (int m = 0; m < AM; ++m) {
        #pragma unroll
        for (int n = 0; n < AN; ++n) {
          int gc = col0 - 1024 + wc * (BN / 2) + n * 16 + cc;
          float bv = bias[gc];
          #pragma unroll
          for (int r = 0; r < 4; ++r) {
            int gr = row0 + wr * (BM / 2) + m * 16 + cr + r;
            float v = fmaxf(acc[m][n][r] + bv, 0.f);
            ((short*)Cout)[(size_t)gr * 1024 + gc] = f2bf(v);
          }
        }
      }
    }
  } else if (EPI == 1) {
    #pragma unroll
    for (int m = 0; m < AM; ++m) {
      #pragma unroll
      for (int n = 0; n < AN; ++n) {
        int gc = col0 + wc * (BN / 2) + n * 16 + cc;
        float bv = bias[gc];
        #pragma unroll
        for (int r = 0; r < 4; ++r) {
          int gr = row0 + wr * (BM / 2) + m * 16 + cr + r;
          float v = fmaxf(acc[m][n][r] + bv, 0.f);
          ((short*)Cout)[(size_t)gr * N + gc] = f2bf(v);
        }
      }
    }
  } else {
    // EPI 3: out[r] = sum_c relu(acc+bias[c])*oW[c] + sum_8 part[r] + c1 + c2
    float rsum[AM * 4];
    #pragma unroll
    for (int i = 0; i < AM * 4; ++i) rsum[i] = 0.f;
    #pragma unroll
    for (int m = 0; m < AM; ++m) {
      #pragma unroll
      for (int n = 0; n < AN; ++n) {
        int gc = col0 + wc * (BN / 2) + n * 16 + cc;
        float bv = bias[gc];
        float ow = w1[gc];
        #pragma unroll
        for (int r = 0; r < 4; ++r) {
          float v = fmaxf(acc[m][n][r] + bv, 0.f);
          rsum[m * 4 + r] = fmaf(v, ow, rsum[m * 4 + r]);
        }
      }
    }
    #pragma unroll
    for (int mask = 1; mask < 16; mask <<= 1)
      #pragma unroll
      for (int i = 0; i < AM * 4; ++i)
        rsum[i] += __shfl_xor(rsum[i], mask, 64);
    if (cc == 0) {
      #pragma unroll
      for (int m = 0; m < AM; ++m)
        #pragma unroll
        for (int r = 0; r < 4; ++r)
          pbuf[wc][wr * (BM / 2) + m * 16 + cr + r] = rsum[m * 4 + r];
    }
    __syncthreads();
    if (tid < BM) {
      int gr = row0 + tid;
      const float4* pp = (const float4*)(partial + (size_t)gr * 8);
      float4 u = pp[0], v = pp[1];
      ((float*)Cout)[gr] = pbuf[0][tid] + pbuf[1][tid]
          + u.x + u.y + u.z + u.w + v.x + v.y + v.z + v.w + c1[0] + c2[0];
    }
  }
}

// ---------------------------------------------------------------------------
extern "C" void kernel_launch(void* const* d_in, const int* in_sizes, int n_in,
                              void* d_out, int out_size, void* d_ws, size_t ws_size,
                              hipStream_t stream) {
  const float* X   = (const float*)d_in[0];
  const float* w1  = (const float*)d_in[1];
  const float* bsc = (const float*)d_in[2];
  const float* nfk = (const float*)d_in[3];
  const int*   f2f = (const int*)d_in[4];
  const float* W0  = (const float*)d_in[5];
  const float* B0  = (const float*)d_in[6];
  const float* W1  = (const float*)d_in[7];
  const float* B1  = (const float*)d_in[8];
  const float* W2  = (const float*)d_in[9];
  const float* B2  = (const float*)d_in[10];
  const float* oW  = (const float*)d_in[11];
  const float* oB  = (const float*)d_in[12];
  float* out = (float*)d_out;

  char* ws = (char*)d_ws;
  short* Xb   = (short*)(ws);                 // 8,388,608
  short* B12  = (short*)(ws + 8388608);       // 4,194,304 (Mt 0..1023, Wt0 1024..2047)
  short* Wt1  = (short*)(ws + 12582912);      // 1,048,576
  short* Wt2  = (short*)(ws + 13631488);      //   262,144
  float* part = (float*)(ws + 13893632);      //   131,072 (4096 x 8)
  short* h0   = (short*)(ws + 14680064);      // 8,388,608
  short* h1   = (short*)(ws + 23068672);      // 4,194,304
  float* nfkT = (float*)(ws + 27262976);      // 6,240,000  -> total 33,502,976 B

  // 1) prep_a: Xb, W-transposes, nfkT
  prep_a_kernel<<<5916, 256, 0, stream>>>(X, nfk, W0, W1, W2,
                                          Xb, B12, Wt1, Wt2, nfkT);
  // 2) prep_b: Mt (coalesced via nfkT)
  prep_b_kernel<<<1024, 256, 0, stream>>>(nfk, nfkT, f2f, B12);
  // 3) fused [T-partials | h0] GEMM: N=2048, K=1024 (tri-skip bx<8)
  gemm_mfma<128, 128, 0><<<dim3(16, 32), 256, 0, stream>>>(
      Xb, B12, B0, h0, 2048, 1024, Xb, w1, part, nullptr, nullptr);
  // 4) h1 = relu(h0 @ W1 + B1): N=512, K=1024, 64x64 tiles (512 blocks)
  gemm_mfma<64, 64, 1><<<dim3(8, 64), 256, 0, stream>>>(
      h0, Wt1, B1, h1, 512, 1024, nullptr, nullptr, nullptr, nullptr, nullptr);
  // 5) gemm4 + out-dot + finalize: N=BN=256, K=512 -> out[]
  gemm_mfma<32, 256, 3><<<dim3(1, 128), 256, 0, stream>>>(
      h1, Wt2, B2, out, 256, 512, nullptr, oW, part, bsc, oB);
}